// Round 9
// baseline (4457.536 us; speedup 1.0000x reference)
//
#include <hip/hip_runtime.h>
#include <stdint.h>

typedef __attribute__((ext_vector_type(8))) short short8;
typedef __attribute__((ext_vector_type(4))) float floatx4;
typedef __attribute__((ext_vector_type(4))) unsigned int uintx4;

#define DEVINL __device__ __forceinline__

DEVINL unsigned short f2bf(float f) {
    unsigned int u = __float_as_uint(f);
    u += 0x7FFFu + ((u >> 16) & 1u);
    return (unsigned short)(u >> 16);
}
DEVINL float bf2f(unsigned short h) {
    return __uint_as_float(((unsigned int)h) << 16);
}
DEVINL float sigf(float x)     { return 1.0f / (1.0f + __expf(-x)); }
DEVINL float tanhfast(float x) { return 2.0f / (1.0f + __expf(-2.0f * x)) - 1.0f; }

// ---------------- problem constants ----------------
constexpr int L_SEQ = 256, BATCH = 16, HID = 800, NGATE = 3200, DIN = 42, NALPHA = 20;
constexpr int HSLOT = BATCH * HID;          // 12800 elements per time slot
constexpr int NBLK_SCAN = 200;              // 2 dirs x 100 blocks (2 waves, 8 units each)
constexpr int FLAG_STRIDE = 32;             // u32s: one flag per 128-B cacheline

// ---------------- workspace layout (bytes) ----------------
constexpr size_t OFF_FLAGS   = 0;                                   // 128 KB padded flags
constexpr size_t SZ_FLAGS    = 131072;
constexpr size_t SZ_WHH_L    = 10240000;                            // per layer: 2*3200*800*2B
constexpr size_t OFF_WHH_HI  = SZ_FLAGS;                            // 2 layers
constexpr size_t OFF_WHH_LO  = OFF_WHH_HI + 2 * SZ_WHH_L;
constexpr size_t SZ_WIH1     = 20480000;                            // 2*3200*1600*2B
constexpr size_t OFF_WIH1_HI = OFF_WHH_LO + 2 * SZ_WHH_L;
constexpr size_t OFF_WIH1_LO = OFF_WIH1_HI + SZ_WIH1;
constexpr size_t OFF_PRE     = OFF_WIH1_LO + SZ_WIH1;               // fp32, shared pre0/pre1
constexpr size_t SZ_PRE      = (size_t)2 * L_SEQ * BATCH * NGATE * 4;  // 104,857,600
constexpr size_t SZ_HP       = (size_t)257 * HSLOT * 4;             // 13,158,400 per packed buf
constexpr size_t OFF_H       = OFF_PRE + SZ_PRE;                    // 4 bufs: F, B, 2F, 2B
constexpr size_t OFF_ANG     = OFF_H + 4 * SZ_HP;                   // 256*16*3 fp32
// total ~228.6 MiB

// =====================================================================
// Pack W_hh (fp32 [2][3200][800]) into per-WAVE MFMA B-fragment streams.
// Wave wg (0..199 per dir) owns units wg*4..wg*4+3; its 16-row N-tile is
// row = u_local*4 + gate  (so MFMA C gives all 4 gates of (unit,batch)
// within the wave). lane l holds W[row=l&15][k0+(l>>4)*8 + 0..7].
// =====================================================================
__global__ __launch_bounds__(256) void pack_whh_kernel(
    const float* __restrict__ w0, const float* __restrict__ w1,
    unsigned short* __restrict__ hi, unsigned short* __restrict__ lo)
{
    size_t g = (size_t)blockIdx.x * 256 + threadIdx.x;   // 1,280,000 total
    if (g >= 1280000) return;
    int l = (int)(g & 63);
    size_t gg = g >> 6;                                   // 20000 fragment ids
    int kk = (int)(gg % 25); gg /= 25;
    int wg = (int)(gg % 200); gg /= 200;
    int d  = (int)(gg % 2);
    int layer = (int)(gg / 2);
    const float* W = layer ? w1 : w0;
    int lr = l & 15;
    int u_local = lr >> 2, gate = lr & 3;
    int unit = wg * 4 + u_local;
    int r = gate * 800 + unit;
    int k0 = kk * 32 + (l >> 4) * 8;
    const float* s = W + ((size_t)d * NGATE + r) * HID + k0;
    short8 vh, vl;
    #pragma unroll
    for (int j = 0; j < 8; ++j) {
        float w = s[j];
        unsigned short h = f2bf(w);
        vh[j] = (short)h;
        vl[j] = (short)f2bf(w - bf2f(h));
    }
    size_t idx = (((size_t)layer * 2 + d) * 200 + wg) * 1600 + (size_t)kk * 64 + l;
    ((short8*)hi)[idx] = vh;
    ((short8*)lo)[idx] = vl;
}

// =====================================================================
// fp32 -> hi/lo bf16 conversion of w_ih_l1 (flat [2][3200][1600]).
// =====================================================================
__global__ __launch_bounds__(256) void conv_wih1_kernel(
    const float* __restrict__ w, unsigned short* __restrict__ hi,
    unsigned short* __restrict__ lo)
{
    size_t g = (size_t)blockIdx.x * 256 + threadIdx.x;   // 1,280,000 groups of 8
    if (g >= 1280000) return;
    const float* s = w + g * 8;
    short8 vh, vl;
    #pragma unroll
    for (int j = 0; j < 8; ++j) {
        float x = s[j];
        unsigned short h = f2bf(x);
        vh[j] = (short)h;
        vl[j] = (short)f2bf(x - bf2f(h));
    }
    ((short8*)hi)[g] = vh;
    ((short8*)lo)[g] = vl;
}

// =====================================================================
// pre0: gate-interleaved layout pre[d][t][b][unit*4+gate] (fp32)
// so the scan reads one dwordx4 = (i,f,g,o) per (b,unit).
// =====================================================================
__global__ __launch_bounds__(256) void pre0_kernel(
    const float* __restrict__ x, const float* __restrict__ wih0,
    const float* __restrict__ b0, float* __restrict__ pre0)
{
    int bid = blockIdx.x;
    int d = bid / 800; int rem = bid % 800;
    int rc = rem / 8, tc = rem % 8;
    int rbase = rc * 32, tbase = tc * 32;
    __shared__ float Wc[32][DIN];
    __shared__ float bias[32];
    __shared__ float xb[BATCH][DIN];
    int tid = threadIdx.x;
    for (int idx = tid; idx < 32 * DIN; idx += 256) {
        int rl = idx / DIN, k = idx % DIN;
        Wc[rl][k] = wih0[((size_t)d * NGATE + rbase + rl) * DIN + k];
    }
    if (tid < 32) bias[tid] = b0[d * NGATE + rbase + tid];
    __syncthreads();
    for (int tt = 0; tt < 32; ++tt) {
        int t = tbase + tt;
        for (int idx = tid; idx < BATCH * DIN; idx += 256) {
            int bb = idx / DIN, k = idx % DIN;
            xb[bb][k] = x[((size_t)bb * L_SEQ + t) * DIN + k];
        }
        __syncthreads();
        for (int o = tid; o < 512; o += 256) {
            int bb = o >> 5, rl = o & 31;
            float s = bias[rl];
            #pragma unroll 6
            for (int k = 0; k < DIN; ++k) s += xb[bb][k] * Wc[rl][k];
            int r = rbase + rl;
            int gate = r / 800, unit = r % 800;
            pre0[((size_t)(d * L_SEQ + t) * BATCH + bb) * NGATE + unit * 4 + gate] = s;
        }
        __syncthreads();
    }
}

// =====================================================================
// Forced-batch system-scope loads: all 50 dwordx4 h-loads for K=800 in
// ONE asm block with a single vmcnt(0) wait (one round trip total).
// =====================================================================
DEVINL void batch_load_50(const uint32_t* base, uintx4* pk) {
    asm volatile(
        "global_load_dwordx4 %0, %50, off sc0 sc1\n\t"
        "global_load_dwordx4 %1, %50, off offset:16 sc0 sc1\n\t"
        "global_load_dwordx4 %2, %50, off offset:128 sc0 sc1\n\t"
        "global_load_dwordx4 %3, %50, off offset:144 sc0 sc1\n\t"
        "global_load_dwordx4 %4, %50, off offset:256 sc0 sc1\n\t"
        "global_load_dwordx4 %5, %50, off offset:272 sc0 sc1\n\t"
        "global_load_dwordx4 %6, %50, off offset:384 sc0 sc1\n\t"
        "global_load_dwordx4 %7, %50, off offset:400 sc0 sc1\n\t"
        "global_load_dwordx4 %8, %50, off offset:512 sc0 sc1\n\t"
        "global_load_dwordx4 %9, %50, off offset:528 sc0 sc1\n\t"
        "global_load_dwordx4 %10, %50, off offset:640 sc0 sc1\n\t"
        "global_load_dwordx4 %11, %50, off offset:656 sc0 sc1\n\t"
        "global_load_dwordx4 %12, %50, off offset:768 sc0 sc1\n\t"
        "global_load_dwordx4 %13, %50, off offset:784 sc0 sc1\n\t"
        "global_load_dwordx4 %14, %50, off offset:896 sc0 sc1\n\t"
        "global_load_dwordx4 %15, %50, off offset:912 sc0 sc1\n\t"
        "global_load_dwordx4 %16, %50, off offset:1024 sc0 sc1\n\t"
        "global_load_dwordx4 %17, %50, off offset:1040 sc0 sc1\n\t"
        "global_load_dwordx4 %18, %50, off offset:1152 sc0 sc1\n\t"
        "global_load_dwordx4 %19, %50, off offset:1168 sc0 sc1\n\t"
        "global_load_dwordx4 %20, %50, off offset:1280 sc0 sc1\n\t"
        "global_load_dwordx4 %21, %50, off offset:1296 sc0 sc1\n\t"
        "global_load_dwordx4 %22, %50, off offset:1408 sc0 sc1\n\t"
        "global_load_dwordx4 %23, %50, off offset:1424 sc0 sc1\n\t"
        "global_load_dwordx4 %24, %50, off offset:1536 sc0 sc1\n\t"
        "global_load_dwordx4 %25, %50, off offset:1552 sc0 sc1\n\t"
        "global_load_dwordx4 %26, %50, off offset:1664 sc0 sc1\n\t"
        "global_load_dwordx4 %27, %50, off offset:1680 sc0 sc1\n\t"
        "global_load_dwordx4 %28, %50, off offset:1792 sc0 sc1\n\t"
        "global_load_dwordx4 %29, %50, off offset:1808 sc0 sc1\n\t"
        "global_load_dwordx4 %30, %50, off offset:1920 sc0 sc1\n\t"
        "global_load_dwordx4 %31, %50, off offset:1936 sc0 sc1\n\t"
        "global_load_dwordx4 %32, %50, off offset:2048 sc0 sc1\n\t"
        "global_load_dwordx4 %33, %50, off offset:2064 sc0 sc1\n\t"
        "global_load_dwordx4 %34, %50, off offset:2176 sc0 sc1\n\t"
        "global_load_dwordx4 %35, %50, off offset:2192 sc0 sc1\n\t"
        "global_load_dwordx4 %36, %50, off offset:2304 sc0 sc1\n\t"
        "global_load_dwordx4 %37, %50, off offset:2320 sc0 sc1\n\t"
        "global_load_dwordx4 %38, %50, off offset:2432 sc0 sc1\n\t"
        "global_load_dwordx4 %39, %50, off offset:2448 sc0 sc1\n\t"
        "global_load_dwordx4 %40, %50, off offset:2560 sc0 sc1\n\t"
        "global_load_dwordx4 %41, %50, off offset:2576 sc0 sc1\n\t"
        "global_load_dwordx4 %42, %50, off offset:2688 sc0 sc1\n\t"
        "global_load_dwordx4 %43, %50, off offset:2704 sc0 sc1\n\t"
        "global_load_dwordx4 %44, %50, off offset:2816 sc0 sc1\n\t"
        "global_load_dwordx4 %45, %50, off offset:2832 sc0 sc1\n\t"
        "global_load_dwordx4 %46, %50, off offset:2944 sc0 sc1\n\t"
        "global_load_dwordx4 %47, %50, off offset:2960 sc0 sc1\n\t"
        "global_load_dwordx4 %48, %50, off offset:3072 sc0 sc1\n\t"
        "global_load_dwordx4 %49, %50, off offset:3088 sc0 sc1\n\t"
        "s_waitcnt vmcnt(0)"
        : "=&v"(pk[0]), "=&v"(pk[1]), "=&v"(pk[2]), "=&v"(pk[3]),
          "=&v"(pk[4]), "=&v"(pk[5]), "=&v"(pk[6]), "=&v"(pk[7]),
          "=&v"(pk[8]), "=&v"(pk[9]), "=&v"(pk[10]), "=&v"(pk[11]),
          "=&v"(pk[12]), "=&v"(pk[13]), "=&v"(pk[14]), "=&v"(pk[15]),
          "=&v"(pk[16]), "=&v"(pk[17]), "=&v"(pk[18]), "=&v"(pk[19]),
          "=&v"(pk[20]), "=&v"(pk[21]), "=&v"(pk[22]), "=&v"(pk[23]),
          "=&v"(pk[24]), "=&v"(pk[25]), "=&v"(pk[26]), "=&v"(pk[27]),
          "=&v"(pk[28]), "=&v"(pk[29]), "=&v"(pk[30]), "=&v"(pk[31]),
          "=&v"(pk[32]), "=&v"(pk[33]), "=&v"(pk[34]), "=&v"(pk[35]),
          "=&v"(pk[36]), "=&v"(pk[37]), "=&v"(pk[38]), "=&v"(pk[39]),
          "=&v"(pk[40]), "=&v"(pk[41]), "=&v"(pk[42]), "=&v"(pk[43]),
          "=&v"(pk[44]), "=&v"(pk[45]), "=&v"(pk[46]), "=&v"(pk[47]),
          "=&v"(pk[48]), "=&v"(pk[49])
        : "v"(base)
        : "memory");
}

DEVINL void unpack_u44(uintx4 p0, uintx4 p1, short8& ah, short8& al) {
    ah[0]=(short)(p0.x&0xffffu); al[0]=(short)(p0.x>>16);
    ah[1]=(short)(p0.y&0xffffu); al[1]=(short)(p0.y>>16);
    ah[2]=(short)(p0.z&0xffffu); al[2]=(short)(p0.z>>16);
    ah[3]=(short)(p0.w&0xffffu); al[3]=(short)(p0.w>>16);
    ah[4]=(short)(p1.x&0xffffu); al[4]=(short)(p1.x>>16);
    ah[5]=(short)(p1.y&0xffffu); al[5]=(short)(p1.y>>16);
    ah[6]=(short)(p1.z&0xffffu); al[6]=(short)(p1.z>>16);
    ah[7]=(short)(p1.w&0xffffu); al[7]=(short)(p1.w>>16);
}

// =====================================================================
// Persistent bidirectional LSTM scan — per-WAVE autonomous version.
// 200 blocks x 128 threads (2 waves). Wave wg owns units wg*4..wg*4+3,
// computes the FULL K=800 recurrence (50-load forced batch, 75 MFMAs),
// regroups gates via a wave-local LDS round trip (NO __syncthreads),
// fuses per-lane (c in a register), stores 1 packed h word per lane,
// drains (1 store), publishes its own flag. Poll: every wave polls all
// 200 same-dir wave flags (padded, contention-free).
// =====================================================================
__global__ __launch_bounds__(128, 1) void scan_kernel(
    const unsigned short* __restrict__ wpackH,
    const unsigned short* __restrict__ wpackL,
    const float* __restrict__ pre,              // [d][t][b][unit*4+gate] fp32
    uint32_t* hFP, uint32_t* hBP,               // packed h archives [257][16][800]
    unsigned int* flags)                        // this launch: [2 dirs][200*32 u32]
{
    __shared__ __align__(16) unsigned short wldsH[25600];   // 2 waves x 25.6 KB
    __shared__ __align__(16) unsigned short wldsL[25600];
    __shared__ __align__(16) float xg[2][64][4];            // per-wave gate scratch
    int tid = threadIdx.x;
    int lane = tid & 63, w = tid >> 6;
    int bid = blockIdx.x;
    int d = bid / 100;
    int wg = (bid % 100) * 2 + w;                // wave-global unit-group 0..199
    unsigned int* dirFlags = flags + (size_t)d * 200 * FLAG_STRIDE;

    {   // each wave stages ITS OWN weight fragments (no cross-wave LDS use)
        const short8* sh = (const short8*)wpackH + ((size_t)d * 200 + wg) * 1600;
        const short8* sl = (const short8*)wpackL + ((size_t)d * 200 + wg) * 1600;
        short8* dh = (short8*)wldsH + (size_t)w * 1600;
        short8* dl = (short8*)wldsL + (size_t)w * 1600;
        for (int i = lane; i < 1600; i += 64) { dh[i] = sh[i]; dl[i] = sl[i]; }
        asm volatile("s_waitcnt lgkmcnt(0)" ::: "memory");
    }

    int m = lane & 15, u = lane >> 4;            // batch, local unit (fuse roles)
    const short8* wH8 = (const short8*)wldsH + (size_t)w * 1600;
    const short8* wL8 = (const short8*)wldsL + (size_t)w * 1600;
    uint32_t* hOutP = d ? hBP : hFP;
    const uint32_t* hInP = d ? hBP : hFP;
    float c = 0.0f;                              // per-lane cell state
    int srcBase = (m >> 2) * 16 + u * 4;         // gate-gather base lane
    int rsel = m & 3;

    for (int s = 0; s < L_SEQ; ++s) {
        int t = d ? (L_SEQ - 1 - s) : s;
        int islot = d ? (t + 1) : t;
        const uint32_t* base = hInP + (size_t)islot * HSLOT + m * HID + u * 8;

        // prefetch (i,f,g,o) pre-activations: one dwordx4 per lane
        floatx4 pv = *(const floatx4*)(pre
            + ((size_t)(d * L_SEQ + t) * BATCH + m) * NGATE
            + ((size_t)wg * 4 + u) * 4);

        if (s > 0) {
            unsigned int need = (unsigned int)s;
            bool ok;
            do {
                unsigned v0 = __hip_atomic_load(&dirFlags[lane * FLAG_STRIDE],
                                __ATOMIC_RELAXED, __HIP_MEMORY_SCOPE_AGENT);
                unsigned v1 = __hip_atomic_load(&dirFlags[(lane + 64) * FLAG_STRIDE],
                                __ATOMIC_RELAXED, __HIP_MEMORY_SCOPE_AGENT);
                unsigned v2 = __hip_atomic_load(&dirFlags[(lane + 128) * FLAG_STRIDE],
                                __ATOMIC_RELAXED, __HIP_MEMORY_SCOPE_AGENT);
                unsigned v3 = (lane < 8)
                    ? __hip_atomic_load(&dirFlags[(lane + 192) * FLAG_STRIDE],
                                __ATOMIC_RELAXED, __HIP_MEMORY_SCOPE_AGENT)
                    : 0xFFFFFFFFu;
                ok = __all(v0 >= need && v1 >= need && v2 >= need && v3 >= need);
            } while (!ok);
        }

        // ---- forced-batch h load (one round trip) + full-K split MFMA ----
        uintx4 pk[50];
        batch_load_50(base, pk);
        floatx4 a0 = {0.f,0.f,0.f,0.f}, a1 = {0.f,0.f,0.f,0.f}, a2 = {0.f,0.f,0.f,0.f};
        #pragma unroll
        for (int kk = 0; kk < 25; ++kk) {
            short8 ah, al;
            unpack_u44(pk[2 * kk], pk[2 * kk + 1], ah, al);
            short8 bh = wH8[kk * 64 + lane];
            short8 bl = wL8[kk * 64 + lane];
            a0 = __builtin_amdgcn_mfma_f32_16x16x32_bf16(ah, bh, a0, 0, 0, 0);
            a1 = __builtin_amdgcn_mfma_f32_16x16x32_bf16(ah, bl, a1, 0, 0, 0);
            a2 = __builtin_amdgcn_mfma_f32_16x16x32_bf16(al, bh, a2, 0, 0, 0);
        }
        floatx4 acc = a0 + a1 + a2;

        // ---- wave-local gate regroup through LDS (no barrier) ----
        *(floatx4*)&xg[w][lane][0] = acc;
        asm volatile("s_waitcnt lgkmcnt(0)" ::: "memory");
        float Gi = xg[w][srcBase + 0][rsel] + pv.x;
        float Gf = xg[w][srcBase + 1][rsel] + pv.y;
        float Gg = xg[w][srcBase + 2][rsel] + pv.z;
        float Go = xg[w][srcBase + 3][rsel] + pv.w;

        // ---- per-lane fuse; c lives in a register ----
        float i_ = sigf(Gi), f_ = sigf(Gf);
        float g_ = tanhfast(Gg), o_ = sigf(Go);
        c = f_ * c + i_ * g_;
        float h = o_ * tanhfast(c);

        int oslot = d ? t : (t + 1);
        size_t oidx = (size_t)oslot * HSLOT + m * HID + (size_t)wg * 4 + u;
        unsigned short hh = f2bf(h);
        uint32_t pko = (uint32_t)hh | ((uint32_t)f2bf(h - bf2f(hh)) << 16);
        __hip_atomic_store(&hOutP[oidx], pko, __ATOMIC_RELAXED,
                           __HIP_MEMORY_SCOPE_AGENT);
        asm volatile("s_waitcnt vmcnt(0)" ::: "memory");   // drain the 1 store
        if (lane == 0)
            __hip_atomic_store(&dirFlags[wg * FLAG_STRIDE],
                               (unsigned int)(s + 1),
                               __ATOMIC_RELAXED, __HIP_MEMORY_SCOPE_AGENT);
    }
}

// =====================================================================
// pre1 = concat(h1f,h1b) @ w_ih_l1.T + b_l1 (fp32, gate-interleaved out)
// split-precision 64x64-tile MFMA GEMM: M=4096 (t,b), N=3200, K=1600.
// =====================================================================
__global__ __launch_bounds__(256, 1) void gemm_pre1_kernel(
    const uint32_t* __restrict__ hFP, const uint32_t* __restrict__ hBP,
    const unsigned short* __restrict__ wih1H, const unsigned short* __restrict__ wih1L,
    const float* __restrict__ b1, float* __restrict__ pre1)
{
    int bid = blockIdx.x;
    int d = bid / 3200; int rst = bid % 3200;
    int mblk = rst / 50, nblk = rst % 50;
    __shared__ __align__(16) unsigned short AslH[64][40];
    __shared__ __align__(16) unsigned short AslL[64][40];
    __shared__ __align__(16) unsigned short BslH[64][40];
    __shared__ __align__(16) unsigned short BslL[64][40];
    int tid = threadIdx.x, lane = tid & 63, w = tid >> 6;
    int wm = w >> 1, wn = w & 1;
    floatx4 acc[2][2] = {};
    int row = tid >> 2, ch = tid & 3;
    int m_row = mblk * 64 + row;
    int t = m_row >> 4, bb = m_row & 15;
    int la = lane & 15, q8 = (lane >> 4) * 8;

    for (int kk = 0; kk < 50; ++kk) {
        int k0 = kk * 32 + ch * 8;
        size_t aoff = (kk < 25)
            ? ((size_t)(t + 1) * HSLOT + bb * HID + k0)
            : ((size_t)t * HSLOT + bb * HID + (k0 - 800));
        const uint32_t* ap = ((kk < 25) ? hFP : hBP) + aoff;
        uint4 p0 = *(const uint4*)ap;
        uint4 p1 = *(const uint4*)(ap + 4);
        short8 ah, al;
        ah[0]=(short)(p0.x&0xffffu); al[0]=(short)(p0.x>>16);
        ah[1]=(short)(p0.y&0xffffu); al[1]=(short)(p0.y>>16);
        ah[2]=(short)(p0.z&0xffffu); al[2]=(short)(p0.z>>16);
        ah[3]=(short)(p0.w&0xffffu); al[3]=(short)(p0.w>>16);
        ah[4]=(short)(p1.x&0xffffu); al[4]=(short)(p1.x>>16);
        ah[5]=(short)(p1.y&0xffffu); al[5]=(short)(p1.y>>16);
        ah[6]=(short)(p1.z&0xffffu); al[6]=(short)(p1.z>>16);
        ah[7]=(short)(p1.w&0xffffu); al[7]=(short)(p1.w>>16);
        *(short8*)&AslH[row][ch * 8] = ah;
        *(short8*)&AslL[row][ch * 8] = al;
        size_t boff = ((size_t)d * NGATE + nblk * 64 + row) * 1600 + kk * 32 + ch * 8;
        *(short8*)&BslH[row][ch * 8] = *(const short8*)(wih1H + boff);
        *(short8*)&BslL[row][ch * 8] = *(const short8*)(wih1L + boff);
        __syncthreads();
        #pragma unroll
        for (int ms = 0; ms < 2; ++ms) {
            short8 fah = *(const short8*)&AslH[wm * 32 + ms * 16 + la][q8];
            short8 fal = *(const short8*)&AslL[wm * 32 + ms * 16 + la][q8];
            #pragma unroll
            for (int ns = 0; ns < 2; ++ns) {
                short8 fbh = *(const short8*)&BslH[wn * 32 + ns * 16 + la][q8];
                short8 fbl = *(const short8*)&BslL[wn * 32 + ns * 16 + la][q8];
                acc[ms][ns] = __builtin_amdgcn_mfma_f32_16x16x32_bf16(fah, fbh, acc[ms][ns], 0, 0, 0);
                acc[ms][ns] = __builtin_amdgcn_mfma_f32_16x16x32_bf16(fah, fbl, acc[ms][ns], 0, 0, 0);
                acc[ms][ns] = __builtin_amdgcn_mfma_f32_16x16x32_bf16(fal, fbh, acc[ms][ns], 0, 0, 0);
            }
        }
        __syncthreads();
    }
    #pragma unroll
    for (int ms = 0; ms < 2; ++ms)
        #pragma unroll
        for (int ns = 0; ns < 2; ++ns)
            #pragma unroll
            for (int rg = 0; rg < 4; ++rg) {
                int mm = mblk * 64 + wm * 32 + ms * 16 + (lane >> 4) * 4 + rg;
                int t2 = mm >> 4, b2 = mm & 15;
                int r = nblk * 64 + wn * 32 + ns * 16 + (lane & 15);
                float val = acc[ms][ns][rg] + b1[d * NGATE + r];
                int gate = r / 800, unit = r % 800;
                pre1[((size_t)(d * L_SEQ + t2) * BATCH + b2) * NGATE + unit * 4 + gate] = val;
            }
}

// =====================================================================
// Head: logits -> softmax -> torsion angles.  One block per t.
// =====================================================================
__global__ __launch_bounds__(256) void head_kernel(
    const uint32_t* __restrict__ h2FP, const uint32_t* __restrict__ h2BP,
    const float* __restrict__ wlin, const float* __restrict__ blin,
    const float* __restrict__ alphabet, float* __restrict__ ang)
{
    int t = blockIdx.x, tid = threadIdx.x;
    __shared__ float lg[BATCH * NALPHA];
    __shared__ float probs[BATCH * NALPHA];
    for (int i = tid; i < BATCH * NALPHA; i += 256) {
        int a = i % NALPHA, b = i / NALPHA;
        size_t fo = (size_t)(t + 1) * HSLOT + b * HID;
        size_t bo = (size_t)t * HSLOT + b * HID;
        const float* wa = wlin + (size_t)a * 1600;
        float s = blin[a];
        #pragma unroll 4
        for (int k = 0; k < HID; ++k) {
            uint32_t uf = h2FP[fo + k], ub = h2BP[bo + k];
            float hf = bf2f((unsigned short)uf) + bf2f((unsigned short)(uf >> 16));
            float hb = bf2f((unsigned short)ub) + bf2f((unsigned short)(ub >> 16));
            s += hf * wa[k] + hb * wa[800 + k];
        }
        lg[b * NALPHA + a] = s;
    }
    __syncthreads();
    if (tid < BATCH) {
        int b = tid;
        float mx = -1e30f;
        for (int a = 0; a < NALPHA; ++a) mx = fmaxf(mx, lg[b * NALPHA + a]);
        float sum = 0.f;
        for (int a = 0; a < NALPHA; ++a) {
            float e = __expf(lg[b * NALPHA + a] - mx);
            probs[b * NALPHA + a] = e; sum += e;
        }
        float inv = 1.0f / sum;
        for (int a = 0; a < NALPHA; ++a) probs[b * NALPHA + a] *= inv;
    }
    __syncthreads();
    if (tid < BATCH * 3) {
        int b = tid / 3, i = tid % 3;
        float ss = 0.f, cc = 0.f;
        for (int a = 0; a < NALPHA; ++a) {
            float al = alphabet[a * 3 + i], p = probs[b * NALPHA + a];
            ss += p * sinf(al); cc += p * cosf(al);
        }
        ang[((size_t)t * BATCH + b) * 3 + i] = atan2f(ss, cc);
    }
}

// =====================================================================
// Sequential NeRF coordinate chain. One block; lane b handles batch b.
// =====================================================================
__global__ __launch_bounds__(64) void coords_kernel(
    const float* __restrict__ ang, float* __restrict__ out)
{
    int b = threadIdx.x;
    if (b >= BATCH) return;
    const float LENS[3] = {145.801f, 152.326f, 132.868f};
    const float ANGS[3] = {2.124f, 1.941f, 2.028f};
    float Ax = 0.f, Ay = 0.f, Az = 1.f;
    float Bx = 0.f, By = 1.f, Bz = 0.f;
    float Cx = 1.f, Cy = 0.f, Cz = 0.f;
    out[((size_t)0 * BATCH + b) * 3 + 0] = 0.f; out[((size_t)0 * BATCH + b) * 3 + 1] = 0.f; out[((size_t)0 * BATCH + b) * 3 + 2] = 1.f;
    out[((size_t)1 * BATCH + b) * 3 + 0] = 0.f; out[((size_t)1 * BATCH + b) * 3 + 1] = 1.f; out[((size_t)1 * BATCH + b) * 3 + 2] = 0.f;
    out[((size_t)2 * BATCH + b) * 3 + 0] = 1.f; out[((size_t)2 * BATCH + b) * 3 + 1] = 0.f; out[((size_t)2 * BATCH + b) * 3 + 2] = 0.f;
    for (int t = 0; t < L_SEQ; ++t) {
        #pragma unroll
        for (int i = 0; i < 3; ++i) {
            float P = ang[((size_t)t * BATCH + b) * 3 + i];
            float R = LENS[i], T = ANGS[i];
            float sT = sinf(T);
            float D2x = -R * cosf(T);
            float D2y = R * cosf(P) * sT;
            float D2z = R * sinf(P) * sT;
            float bx = Cx - Bx, by = Cy - By, bz = Cz - Bz;
            float binv = 1.0f / sqrtf(bx * bx + by * by + bz * bz);
            bx *= binv; by *= binv; bz *= binv;
            float ux = Bx - Ax, uy = By - Ay, uz = Bz - Az;
            float nx = uy * bz - uz * by;
            float ny = uz * bx - ux * bz;
            float nz = ux * by - uy * bx;
            float ninv = 1.0f / sqrtf(nx * nx + ny * ny + nz * nz);
            nx *= ninv; ny *= ninv; nz *= ninv;
            float cxx = ny * bz - nz * by;
            float cxy = nz * bx - nx * bz;
            float cxz = nx * by - ny * bx;
            float Dx = bx * D2x + cxx * D2y + nx * D2z + Cx;
            float Dy = by * D2x + cxy * D2y + ny * D2z + Cy;
            float Dz = bz * D2x + cxz * D2y + nz * D2z + Cz;
            size_t orow = 3 + (size_t)t * 3 + i;
            out[(orow * BATCH + b) * 3 + 0] = Dx;
            out[(orow * BATCH + b) * 3 + 1] = Dy;
            out[(orow * BATCH + b) * 3 + 2] = Dz;
            Ax = Bx; Ay = By; Az = Bz;
            Bx = Cx; By = Cy; Bz = Cz;
            Cx = Dx; Cy = Dy; Cz = Dz;
        }
    }
}

// =====================================================================
extern "C" void kernel_launch(void* const* d_in, const int* in_sizes, int n_in,
                              void* d_out, int out_size, void* d_ws, size_t ws_size,
                              hipStream_t stream)
{
    const float* x       = (const float*)d_in[0];
    const float* w_ih_l0 = (const float*)d_in[1];
    const float* w_hh_l0 = (const float*)d_in[2];
    const float* b_l0    = (const float*)d_in[3];
    const float* w_ih_l1 = (const float*)d_in[4];
    const float* w_hh_l1 = (const float*)d_in[5];
    const float* b_l1    = (const float*)d_in[6];
    const float* w_lin   = (const float*)d_in[7];
    const float* b_lin   = (const float*)d_in[8];
    const float* alphabet= (const float*)d_in[9];
    (void)in_sizes; (void)n_in; (void)out_size; (void)ws_size;

    char* ws = (char*)d_ws;
    unsigned int*   flags   = (unsigned int*)(ws + OFF_FLAGS);
    unsigned short* whhHi   = (unsigned short*)(ws + OFF_WHH_HI);
    unsigned short* whhLo   = (unsigned short*)(ws + OFF_WHH_LO);
    unsigned short* wih1Hi  = (unsigned short*)(ws + OFF_WIH1_HI);
    unsigned short* wih1Lo  = (unsigned short*)(ws + OFF_WIH1_LO);
    float*          pre     = (float*)(ws + OFF_PRE);       // pre0 then pre1 (aliased)
    uint32_t*       hFP     = (uint32_t*)(ws + OFF_H + 0 * SZ_HP);
    uint32_t*       hBP     = (uint32_t*)(ws + OFF_H + 1 * SZ_HP);
    uint32_t*       h2FP    = (uint32_t*)(ws + OFF_H + 2 * SZ_HP);
    uint32_t*       h2BP    = (uint32_t*)(ws + OFF_H + 3 * SZ_HP);
    float*          angbuf  = (float*)(ws + OFF_ANG);

    // zero flags (poison 0xAA would false-pass polls) + boundary h slots
    hipMemsetAsync(ws + OFF_FLAGS, 0, SZ_FLAGS, stream);
    const size_t slotB = (size_t)HSLOT * 4;
    hipMemsetAsync((char*)hFP, 0, slotB, stream);
    hipMemsetAsync((char*)hBP + 256 * slotB, 0, slotB, stream);
    hipMemsetAsync((char*)h2FP, 0, slotB, stream);
    hipMemsetAsync((char*)h2BP + 256 * slotB, 0, slotB, stream);

    pack_whh_kernel<<<5000, 256, 0, stream>>>(w_hh_l0, w_hh_l1, whhHi, whhLo);
    conv_wih1_kernel<<<5000, 256, 0, stream>>>(w_ih_l1, wih1Hi, wih1Lo);
    pre0_kernel<<<1600, 256, 0, stream>>>(x, w_ih_l0, b_l0, pre);

    // layer 0 bidirectional scan (flag region 0)
    scan_kernel<<<NBLK_SCAN, 128, 0, stream>>>(whhHi, whhLo, pre, hFP, hBP, flags);
    // layer 1 input projection (overwrites pre in place: pre0 dead, pre1 live)
    gemm_pre1_kernel<<<6400, 256, 0, stream>>>(hFP, hBP, wih1Hi, wih1Lo, b_l1, pre);
    // layer 1 bidirectional scan (flag region 1)
    constexpr size_t LOFF = SZ_WHH_L / 2;  // ushort elements per layer
    scan_kernel<<<NBLK_SCAN, 128, 0, stream>>>(whhHi + LOFF, whhLo + LOFF, pre,
                                               h2FP, h2BP, flags + 2 * 200 * FLAG_STRIDE);

    head_kernel<<<L_SEQ, 256, 0, stream>>>(h2FP, h2BP, w_lin, b_lin, alphabet, angbuf);
    coords_kernel<<<1, 64, 0, stream>>>(angbuf, (float*)d_out);
}